// Round 8
// baseline (443.905 us; speedup 1.0000x reference)
//
#include <hip/hip_runtime.h>

#define N_ATOM 30000
#define N_PAIR 1000000
#define N_TRI  4000000
#define N_SF   16
#define FP_ELEMS (N_ATOM * N_SF)

#define ASH  5                      // atoms per coarse bucket = 32
#define APB  32
#define NCB  938                    // ceil(30000/32)
#define NSUB 8                      // XCD sub-buckets
#define NSEG (NCB * NSUB)           // 7504
#define OVF_CNT_IDX NSEG
#define OVF_CAP 131072
#define TILE 4096
#define PER_TH 16
#define NTILES ((N_TRI + TILE - 1) / TILE)   // 977
#define NWAVE 4                     // waves per block (256 threads)

// workspace layout (bytes) — pack is 8MB quantized (uint2); borderline
// triplets are re-evaluated EXACTLY from the raw inputs in ovf3.
#define OFF_CCNT  0ULL              //  32 KiB: NSEG+1 ints
#define OFF_IKMAX 65536ULL          //  4,000,000  (int per pair)
#define OFF_AOFP  4065536ULL        //  2,000,000  (ushort per pair)
#define OFF_FLAG  6065536ULL        //  1,000,000  (byte per pair)
#define OFF_OVF   7065536ULL        //  1,048,576  (int2 * 131072)
#define OFF_PACK  8114112ULL        //  8,000,000  (uint2 {dx20|dy20|dz20})
#define OFF_CB    16114112ULL       // cbucket: NSEG * cap * 8

// 20-bit fixed-point over [-6, 6]; coordinate error <= DQ/2 = 5.72e-6.
// d2jk error bound: 3 * 2*|j|*2*(DQ/2) <= 3*2*12*1.14e-5 = 8.22e-4 < EPS band.
#define QSCALE 87381.333333f        // 2^20 / 12
#define DQ     1.14440918e-5f       // 12 / 2^20
#define EPS_D2 2.0e-3f              // borderline band half-width on d2jk

__device__ __forceinline__ uint2 enc_pack(float x, float y, float z)
{
    unsigned qx = (unsigned)fminf(fmaxf(fmaf(x + 6.0f, QSCALE, 0.5f), 0.0f), 1048575.0f);
    unsigned qy = (unsigned)fminf(fmaxf(fmaf(y + 6.0f, QSCALE, 0.5f), 0.0f), 1048575.0f);
    unsigned qz = (unsigned)fminf(fmaxf(fmaf(z + 6.0f, QSCALE, 0.5f), 0.0f), 1048575.0f);
    uint2 u;
    u.x = qx | (qy << 20);
    u.y = (qy >> 12) | (qz << 8);
    return u;
}

// ---------------------------------------------------------------------------
// quantized geometry math. Returns: 0 = certainly excluded, 1 = process
// (A8/R2 filled), 2 = borderline (defer to exact path).
__device__ __forceinline__ int tri_math_q(
    uint2 U, uint2 V, float A8[8], float& R2)
{
    float ax = fmaf((float)(U.x & 0xFFFFF), DQ, -6.0f);
    float ay = fmaf((float)(((U.x >> 20) | (U.y << 12)) & 0xFFFFF), DQ, -6.0f);
    float az = fmaf((float)((U.y >> 8) & 0xFFFFF), DQ, -6.0f);
    float bx = fmaf((float)(V.x & 0xFFFFF), DQ, -6.0f);
    float by = fmaf((float)(((V.x >> 20) | (V.y << 12)) & 0xFFFFF), DQ, -6.0f);
    float bz = fmaf((float)((V.y >> 8) & 0xFFFFF), DQ, -6.0f);
    float d2ij = fmaf(ax, ax, fmaf(ay, ay, az * az));
    float d2ik = fmaf(bx, bx, fmaf(by, by, bz * bz));
    float jx = bx - ax, jy = by - ay, jz = bz - az;
    float d2jk = fmaf(jx, jx, fmaf(jy, jy, jz * jz));
    float dev = d2jk - 36.0f;
    if (fabsf(dev) < EPS_D2) return 2;     // borderline: exact path decides
    if (dev > 0.0f) return 0;              // certainly outside cutoff
    float dij = sqrtf(d2ij);
    float dik = sqrtf(d2ik);
    float djk = sqrtf(d2jk);
    const float PI_OVER_RC = 0.5235987755982988f;
    float fcij = 0.5f * (__cosf(PI_OVER_RC * dij) + 1.0f);
    float fcik = 0.5f * (__cosf(PI_OVER_RC * dik) + 1.0f);
    float fcjk = 0.5f * (__cosf(PI_OVER_RC * djk) + 1.0f);
    float dot = fmaf(ax, bx, fmaf(ay, by, az * bz));
    float cosv = dot / (dij * dik);
    R2 = d2ij + d2ik + d2jk;
    float FCt = fcij * fcik * fcjk;
    float bm = fmaxf(1.0f - cosv, 0.0f);
    float bp = fmaxf(1.0f + cosv, 0.0f);
    float bm2 = bm * bm, bp2 = bp * bp;
    float bm4 = bm2 * bm2, bp4 = bp2 * bp2;
    float bm8 = bm4 * bm4, bp8 = bp4 * bp4;
    A8[0] = FCt * bm;              A8[1] = FCt * bp;
    A8[2] = 0.5f * FCt * bm2;      A8[3] = 0.5f * FCt * bp2;
    A8[4] = 0.125f * FCt * bm4;    A8[5] = 0.125f * FCt * bp4;
    A8[6] = 0.0078125f * FCt * bm8; A8[7] = 0.0078125f * FCt * bp8;
    return 1;
}

// exact math from raw inputs (ovf3 / legacy)
__device__ __forceinline__ bool tri_math_raw(
    float4 A, float4 B, float A8[8], float& R2)
{
    float ax = A.x, ay = A.y, az = A.z, fcij = A.w;
    float bx = B.x, by = B.y, bz = B.z, fcik = B.w;
    float d2ij = fmaf(ax, ax, fmaf(ay, ay, az * az));
    float d2ik = fmaf(bx, bx, fmaf(by, by, bz * bz));
    float jx = bx - ax, jy = by - ay, jz = bz - az;
    float d2jk = fmaf(jx, jx, fmaf(jy, jy, jz * jz));
    if (!(d2jk < 36.0f)) return false;
    float dij = sqrtf(d2ij);
    float dik = sqrtf(d2ik);
    float djk = sqrtf(d2jk);
    const float PI_OVER_RC = 0.5235987755982988f;
    float fcjk = 0.5f * (__cosf(PI_OVER_RC * djk) + 1.0f);
    float dot = fmaf(ax, bx, fmaf(ay, by, az * bz));
    float cosv = dot / (dij * dik);
    R2 = d2ij + d2ik + d2jk;
    float FCt = fcij * fcik * fcjk;
    float bm = fmaxf(1.0f - cosv, 0.0f);
    float bp = fmaxf(1.0f + cosv, 0.0f);
    float bm2 = bm * bm, bp2 = bp * bp;
    float bm4 = bm2 * bm2, bp4 = bp2 * bp2;
    float bm8 = bm4 * bm4, bp8 = bp4 * bp4;
    A8[0] = FCt * bm;              A8[1] = FCt * bp;
    A8[2] = 0.5f * FCt * bm2;      A8[3] = 0.5f * FCt * bp2;
    A8[4] = 0.125f * FCt * bm4;    A8[5] = 0.125f * FCt * bp4;
    A8[6] = 0.0078125f * FCt * bm8; A8[7] = 0.0078125f * FCt * bp8;
    return true;
}

// exp(-eta_s * R2) for all 16 eta via 4 expf + exact x2/sum chains:
// eta = {.01,.014,.02,.028,.04,.056,.08,.11,.16,.22,.32,.45,.63,.72,.9,1.}
#define SF_ACCUM(lrow, A8, R2, ATOMIC) do {                                   \
    float e0  = __expf(-0.01f  * (R2));                                       \
    float e1  = __expf(-0.014f * (R2));                                       \
    float e7  = __expf(-0.11f  * (R2));                                       \
    float e11 = __expf(-0.45f  * (R2));                                       \
    float e2 = e0*e0,  e3 = e1*e1;                                            \
    float e4 = e2*e2,  e5 = e3*e3;                                            \
    float e6 = e4*e4,  e9 = e7*e7;                                            \
    float e8 = e6*e6,  e14 = e11*e11;                                         \
    float e10 = e8*e8;                                                        \
    float e12 = e11*e8*e2;                                                    \
    float e13 = e10*e10*e6;                                                   \
    float e15 = e14*e6*e2;                                                    \
    ATOMIC(&(lrow)[0],  (A8)[0]*e0);  ATOMIC(&(lrow)[1],  (A8)[1]*e1);        \
    ATOMIC(&(lrow)[2],  (A8)[2]*e2);  ATOMIC(&(lrow)[3],  (A8)[3]*e3);        \
    ATOMIC(&(lrow)[4],  (A8)[4]*e4);  ATOMIC(&(lrow)[5],  (A8)[5]*e5);        \
    ATOMIC(&(lrow)[6],  (A8)[6]*e6);  ATOMIC(&(lrow)[7],  (A8)[7]*e7);        \
    ATOMIC(&(lrow)[8],  (A8)[0]*e8);  ATOMIC(&(lrow)[9],  (A8)[1]*e9);        \
    ATOMIC(&(lrow)[10], (A8)[2]*e10); ATOMIC(&(lrow)[11], (A8)[3]*e11);       \
    ATOMIC(&(lrow)[12], (A8)[4]*e12); ATOMIC(&(lrow)[13], (A8)[5]*e13);       \
    ATOMIC(&(lrow)[14], (A8)[6]*e14); ATOMIC(&(lrow)[15], (A8)[7]*e15);       \
} while (0)

#define ATOM_LDS(p, v)  atomicAdd((p), (v))
#define ATOM_GLB(p, v)  unsafeAtomicAdd((p), (v))

// ---------------------------------------------------------------------------
// fast path
// ---------------------------------------------------------------------------

__global__ __launch_bounds__(256) void prep2(
    const int2* __restrict__ ind2, const float* __restrict__ diff,
    int* __restrict__ ccnt, int* __restrict__ ikmax,
    unsigned short* __restrict__ aofp, unsigned char* __restrict__ flag,
    uint2* __restrict__ pack, float* __restrict__ out)
{
    int p = blockIdx.x * blockDim.x + threadIdx.x;
    if (p <= NSEG) ccnt[p] = 0;     // includes overflow counter
    if (p < FP_ELEMS) out[p] = 0.0f;  // zero fp rows (reduce4/ovf3 atomic-add)
    if (p >= N_PAIR) return;
    ikmax[p] = -1;
    flag[p] = 0;
    aofp[p] = (unsigned short)ind2[p].x;
    pack[p] = enc_pack(diff[3 * p + 0], diff[3 * p + 1], diff[3 * p + 2]);
}

// LDS-staged counting scatter into coarse buckets (XCD sub-bucketed).
__global__ __launch_bounds__(256) void bin3(
    const int2* __restrict__ ind3, const unsigned short* __restrict__ aofp,
    int* __restrict__ ccnt, int2* __restrict__ cbucket,
    int2* __restrict__ ovf, int cap)
{
    __shared__ int lcnt[NCB];
    __shared__ int lbase[NCB];
    const int thr = threadIdx.x;
    const int sub = blockIdx.x & (NSUB - 1);
    const long long t0 = (long long)blockIdx.x * TILE;

    for (int i = thr; i < NCB; i += 256) lcnt[i] = 0;
    __syncthreads();

    int myatom[PER_TH];
    int myslot[PER_TH];
#pragma unroll
    for (int j = 0; j < PER_TH; ++j) {
        long long t = t0 + j * 256 + thr;
        int a = 0, s = -1;
        if (t < N_TRI) {
            int ij = ind3[t].x;
            a = aofp[ij];
            s = atomicAdd(&lcnt[a >> ASH], 1);
        }
        myatom[j] = a;
        myslot[j] = s;
    }
    __syncthreads();
    for (int c = thr; c < NCB; c += 256) {
        int n = lcnt[c];
        lbase[c] = n ? atomicAdd(&ccnt[c * NSUB + sub], n) : 0;
    }
    __syncthreads();
#pragma unroll
    for (int j = 0; j < PER_TH; ++j) {
        long long t = t0 + j * 256 + thr;
        if (t >= N_TRI) continue;
        int a = myatom[j];
        int c = a >> ASH;
        int slot = lbase[c] + myslot[j];
        int2 pr = ind3[t];
        if (slot < cap) {
            int2 e;
            e.x = pr.x | ((a & (APB - 1)) << 20);   // ij < 2^20, pack a5 above
            e.y = pr.y;
            cbucket[(size_t)(c * NSUB + sub) * cap + slot] = e;
        } else {
            int o = atomicAdd(&ccnt[OVF_CNT_IDX], 1);
            if (o < OVF_CAP) ovf[o] = pr;
        }
    }
}

// one block per (coarse bucket, sub) segment: 7504 blocks, ~533 triplets each.
// Hot pack is 8MB quantized -> doubled XCD-L2 hit rate on the 8M random loads
// (the measured latency-bound floor). Mask decisions with |d2jk-36| < 2e-3
// (quant error bound 8.2e-4, margin 2.4x) are deferred to the exact path.
__global__ __launch_bounds__(256) void reduce4(
    const int* __restrict__ ccnt, const int2* __restrict__ cbucket, int cap,
    const uint2* __restrict__ pack,
    int* __restrict__ ikmax, unsigned char* __restrict__ flag,
    int* __restrict__ ovfcnt, int2* __restrict__ ovf,
    float* __restrict__ out)
{
    __shared__ float lacc[NWAVE][APB * 17];   // per-wave replicas, +1 pad/row
    const int seg = blockIdx.x;
    const int b = seg >> 3;               // coarse bucket
    const int thr = threadIdx.x;
    const int wid = thr >> 6;
    for (int i = thr; i < NWAVE * APB * 17; i += 256)
        ((float*)lacc)[i] = 0.0f;
    __syncthreads();

    int n = ccnt[seg];
    n = min(n, cap);
    const int2* segp = cbucket + (size_t)seg * cap;
    for (int i = thr; i < n; i += 256) {
        int2 e = segp[i];
        int a5 = (e.x >> 20) & (APB - 1);
        int ij = e.x & 0xFFFFF;
        int ik = e.y;
        uint2 U = pack[ij];
        uint2 V = pack[ik];
        float A8[8], R2;
        int code = tri_math_q(U, V, A8, R2);
        if (code == 0) continue;
        if (code == 2) {                       // borderline -> exact path
            int o = atomicAdd(ovfcnt, 1);
            if (o < OVF_CAP) { int2 pr; pr.x = ij; pr.y = ik; ovf[o] = pr; }
            continue;
        }
        flag[ij] = 1;
        atomicMax(&ikmax[ik], (b << ASH) + a5);
        float* lrow = &lacc[wid][a5 * 17];
        SF_ACCUM(lrow, A8, R2, ATOM_LDS);
    }
    __syncthreads();
    for (int t = thr; t < APB * N_SF; t += 256) {
        int atom = (b << ASH) + (t >> 4);
        int idx = (t >> 4) * 17 + (t & 15);
        float v = lacc[0][idx] + lacc[1][idx] + lacc[2][idx] + lacc[3][idx];
        if (atom < N_ATOM && v != 0.0f)
            unsafeAtomicAdd(out + (size_t)atom * N_SF + (t & 15), v);
    }
}

// exact path: bucket-overflow (from bin3) + borderline (from reduce4)
// triplets, evaluated from the RAW inputs — mask decision is bit-exact.
__global__ __launch_bounds__(256) void ovf3(
    const int* __restrict__ ccnt, const int2* __restrict__ ovf,
    const float* __restrict__ diff, const float* __restrict__ fc,
    const unsigned short* __restrict__ aofp,
    int* __restrict__ ikmax, unsigned char* __restrict__ flag,
    float* __restrict__ out)
{
    int i = blockIdx.x * blockDim.x + threadIdx.x;
    int n = ccnt[OVF_CNT_IDX];
    if (n > OVF_CAP) n = OVF_CAP;
    if (i >= n) return;
    int2 pr = ovf[i];
    int ij = pr.x, ik = pr.y;
    float4 A, B;
    A.x = diff[3 * ij + 0]; A.y = diff[3 * ij + 1]; A.z = diff[3 * ij + 2]; A.w = fc[ij];
    B.x = diff[3 * ik + 0]; B.y = diff[3 * ik + 1]; B.z = diff[3 * ik + 2]; B.w = fc[ik];
    float A8[8], R2;
    if (!tri_math_raw(A, B, A8, R2)) return;
    int atom = aofp[ij];
    flag[ij] = 1;
    atomicMax(&ikmax[ik], atom);
    float* base = out + (size_t)atom * N_SF;
    SF_ACCUM(base, A8, R2, ATOM_GLB);
}

__global__ __launch_bounds__(256) void fin3(
    const int* __restrict__ ikmax, const unsigned char* __restrict__ flag,
    const unsigned short* __restrict__ aofp, float* __restrict__ out)
{
    int p = blockIdx.x * blockDim.x + threadIdx.x;
    if (p >= N_PAIR) return;
    int v = ikmax[p];
    if (flag[p]) { int a = aofp[p]; v = v > a ? v : a; }
    float* jf = out + FP_ELEMS;
    jf[2 * p + 0] = (float)p;
    jf[2 * p + 1] = (float)v;
}

// ---------------------------------------------------------------------------
// legacy fallback (exact, reads raw inputs)
// ---------------------------------------------------------------------------

__global__ __launch_bounds__(256) void init_legacy(float* __restrict__ out) {
    int i = blockIdx.x * blockDim.x + threadIdx.x;
    if (i < FP_ELEMS) out[i] = 0.0f;
    if (i < N_PAIR) ((int*)out + FP_ELEMS)[2 * i + 1] = -1;
}

__global__ __launch_bounds__(256) void tri_legacy(
    const int* __restrict__ ind2, const int2* __restrict__ ind3,
    const float* __restrict__ dist, const float* __restrict__ diff,
    const float* __restrict__ fc, float* __restrict__ out) {
    int t = blockIdx.x * blockDim.x + threadIdx.x;
    if (t >= N_TRI) return;
    int2 pr = ind3[t];
    int ij = pr.x, ik = pr.y;
    float4 A, B;
    A.x = diff[3 * ij + 0]; A.y = diff[3 * ij + 1]; A.z = diff[3 * ij + 2]; A.w = fc[ij];
    B.x = diff[3 * ik + 0]; B.y = diff[3 * ik + 1]; B.z = diff[3 * ik + 2]; B.w = fc[ik];
    float A8[8], R2;
    if (!tri_math_raw(A, B, A8, R2)) return;
    int atom = ind2[2 * ij];
    int* jac = (int*)out + FP_ELEMS;
    atomicMax(&jac[2 * ij + 1], atom);
    atomicMax(&jac[2 * ik + 1], atom);
    float* base = out + (size_t)atom * N_SF;
    SF_ACCUM(base, A8, R2, ATOM_GLB);
}

__global__ __launch_bounds__(256) void fin_legacy(float* __restrict__ out) {
    int p = blockIdx.x * blockDim.x + threadIdx.x;
    if (p >= N_PAIR) return;
    int* jac = (int*)out + FP_ELEMS;
    int v = jac[2 * p + 1];
    float* jf = (float*)jac;
    jf[2 * p + 0] = (float)p;
    jf[2 * p + 1] = (float)v;
}

// ---------------------------------------------------------------------------

extern "C" void kernel_launch(void* const* d_in, const int* in_sizes, int n_in,
                              void* d_out, int out_size, void* d_ws, size_t ws_size,
                              hipStream_t stream) {
    const int2*  ind2 = (const int2*)d_in[0];
    const int2*  ind3 = (const int2*)d_in[1];
    const float* dist = (const float*)d_in[2];
    const float* diff = (const float*)d_in[3];
    const float* fc   = (const float*)d_in[5];
    float* out = (float*)d_out;

    const size_t seg_stride = (size_t)NSEG * sizeof(int2);
    const size_t need_min = OFF_CB + seg_stride * 608;

    if (ws_size >= need_min) {
        char* ws = (char*)d_ws;
        int* ccnt            = (int*)(ws + OFF_CCNT);
        int* ikmax           = (int*)(ws + OFF_IKMAX);
        unsigned short* aofp = (unsigned short*)(ws + OFF_AOFP);
        unsigned char* flag  = (unsigned char*)(ws + OFF_FLAG);
        int2* ovf            = (int2*)(ws + OFF_OVF);
        uint2* pack          = (uint2*)(ws + OFF_PACK);
        int2* cbucket        = (int2*)(ws + OFF_CB);
        int cap = (int)((ws_size - OFF_CB) / seg_stride);
        if (cap > 1024) cap = 1024;

        int pb = (N_PAIR + 255) / 256;
        prep2<<<pb, 256, 0, stream>>>(ind2, diff, ccnt, ikmax, aofp, flag, pack, out);
        bin3<<<NTILES, 256, 0, stream>>>(ind3, aofp, ccnt, cbucket, ovf, cap);
        reduce4<<<NSEG, 256, 0, stream>>>(ccnt, cbucket, cap, pack, ikmax, flag,
                                          &ccnt[OVF_CNT_IDX], ovf, out);
        ovf3<<<OVF_CAP / 256, 256, 0, stream>>>(ccnt, ovf, diff, fc, aofp, ikmax, flag, out);
        fin3<<<pb, 256, 0, stream>>>(ikmax, flag, aofp, out);
    } else {
        init_legacy<<<(N_PAIR + 255) / 256, 256, 0, stream>>>(out);
        tri_legacy<<<(N_TRI + 255) / 256, 256, 0, stream>>>((const int*)d_in[0], ind3, dist, diff, fc, out);
        fin_legacy<<<(N_PAIR + 255) / 256, 256, 0, stream>>>(out);
    }
    (void)dist; (void)in_sizes; (void)n_in; (void)out_size;
}